// Round 2
// baseline (23.855 us; speedup 1.0000x reference)
//
#include <hip/hip_runtime.h>
#include <math.h>

#define L_TAPS 16
#define M_FFT  64
#define SMAX   256     // max supported S (= Ns+2); bench uses S=14
#define SMK_MAX 2048   // max supported S*MK; bench uses 1120

__global__ __launch_bounds__(256) void channel_kernel(
    const float* __restrict__ xr, const float* __restrict__ xi,
    const float* __restrict__ cr, const float* __restrict__ ci,
    const int*   __restrict__ ns_ptr,
    float* __restrict__ out,      // see `interleaved` flag for layout
    int NP, int SMK, int interleaved)
{
    __shared__ float  s_cr[L_TAPS], s_ci[L_TAPS];
    __shared__ float2 s_w[SMAX];
    __shared__ unsigned short s_smap[SMK_MAX];

    const int np  = blockIdx.x;
    const int tid = threadIdx.x;
    const int S   = ns_ptr[0] + 2;   // N_PILOT = 2
    const int MK  = SMK / S;

    // ---- stage cof into LDS ----
    if (tid < L_TAPS) {
        s_cr[tid] = cr[(size_t)np * L_TAPS + tid];
        s_ci[tid] = ci[(size_t)np * L_TAPS + tid];
    }
    __syncthreads();

    // ---- s-index lookup map: s = i / MK ----
    for (int i = tid; i < SMK; i += 256) {
        s_smap[i] = (unsigned short)(i / MK);
    }

    // ---- weight[s] = sum_l cof[l] * exp(i * 2*pi*cos(angle_l)*fd * t_s) ----
    if (tid < S && tid < SMAX) {
        const float two_pi = 6.2831853071795864f;
        const float dt     = 0.0005f / 14.0f;          // reference hard-codes /14
        const float fd     = 100.0f / 3.0e8f * 3.0e9f; // = 1000 Hz
        const float t      = tid * dt;
        float wr_ = 0.f, wi_ = 0.f;
        #pragma unroll
        for (int l = 0; l < L_TAPS; ++l) {
            float angle = l * (two_pi / 15.0f);        // linspace(0, 2pi, 16)
            float phase = two_pi * __cosf(angle) * fd * t;
            float sp, cp;
            __sincosf(phase, &sp, &cp);
            wr_ += s_cr[l] * cp - s_ci[l] * sp;
            wi_ += s_cr[l] * sp + s_ci[l] * cp;
        }
        s_w[tid] = make_float2(wr_, wi_);
    }

    // ---- H_t[m] = sum_l cof[l] * exp(-2*pi*i*l*m/64)  (threads 64..127) ----
    if (tid >= 64 && tid < 64 + M_FFT) {
        const int m = tid - 64;
        float hr = 0.f, hi = 0.f;
        #pragma unroll
        for (int l = 0; l < L_TAPS; ++l) {
            int ml = (m * l) & (M_FFT - 1);
            float theta = -(float)ml * (6.2831853071795864f / 64.0f);
            float sp, cp;
            __sincosf(theta, &sp, &cp);
            hr += s_cr[l] * cp - s_ci[l] * sp;
            hi += s_cr[l] * sp + s_ci[l] * cp;
        }
        const size_t hbase = (size_t)NP * SMK;
        if (interleaved) {
            ((float2*)out)[hbase + (size_t)np * M_FFT + m] = make_float2(hr, hi);
        } else {
            out[hbase + (size_t)np * M_FFT + m] = hr;   // real part only
        }
    }
    __syncthreads();

    // ---- streaming: out[i] = Re/Complex of x[i] * weight[s(i)] ----
    const size_t base = (size_t)np * SMK;
    if ((MK & 3) == 0 && (SMK & 3) == 0) {
        // vectorized: float4 never straddles an s boundary (MK % 4 == 0)
        const float4* xr4 = (const float4*)(xr + base);
        const float4* xi4 = (const float4*)(xi + base);
        const int nvec = SMK >> 2;
        for (int i = tid; i < nvec; i += 256) {
            float4 a = xr4[i];
            float4 b = xi4[i];
            float2 w = s_w[s_smap[i << 2]];
            float4 re;
            re.x = a.x * w.x - b.x * w.y;
            re.y = a.y * w.x - b.y * w.y;
            re.z = a.z * w.x - b.z * w.y;
            re.w = a.w * w.x - b.w * w.y;
            if (interleaved) {
                float2* o = ((float2*)out) + base;
                o[(i << 2) + 0] = make_float2(re.x, a.x * w.y + b.x * w.x);
                o[(i << 2) + 1] = make_float2(re.y, a.y * w.y + b.y * w.x);
                o[(i << 2) + 2] = make_float2(re.z, a.z * w.y + b.z * w.x);
                o[(i << 2) + 3] = make_float2(re.w, a.w * w.y + b.w * w.x);
            } else {
                ((float4*)(out + base))[i] = re;
            }
        }
    } else {
        for (int i = tid; i < SMK; i += 256) {
            float xre = xr[base + i];
            float xim = xi[base + i];
            float2 w  = s_w[s_smap[i]];
            if (interleaved) {
                ((float2*)out)[base + i] = make_float2(xre * w.x - xim * w.y,
                                                       xre * w.y + xim * w.x);
            } else {
                out[base + i] = xre * w.x - xim * w.y;
            }
        }
    }
}

extern "C" void kernel_launch(void* const* d_in, const int* in_sizes, int n_in,
                              void* d_out, int out_size, void* d_ws, size_t ws_size,
                              hipStream_t stream) {
    const float* xr = (const float*)d_in[0];
    const float* xi = (const float*)d_in[1];
    const float* cr = (const float*)d_in[2];
    const float* ci = (const float*)d_in[3];
    const int*   ns = (const int*)  d_in[4];

    const int NP  = in_sizes[2] / L_TAPS;   // N*P = 8192
    const int SMK = in_sizes[0] / NP;       // 1120

    const int elems = NP * SMK + NP * M_FFT;          // logical complex elements
    const int interleaved = (out_size == 2 * elems) ? 1 : 0;

    channel_kernel<<<NP, 256, 0, stream>>>(xr, xi, cr, ci, ns,
                                           (float*)d_out, NP, SMK, interleaved);
}